// Round 2
// baseline (330.804 us; speedup 1.0000x reference)
//
#include <hip/hip_runtime.h>

#define NN 50000
#define NE 800000
#define NG 512
#define DD 128
#define CAP 64

// ---- degree count + bucket scatter (int atomics only) ----
__global__ __launch_bounds__(256) void k_deg_bucket(
    const int* __restrict__ src, const int* __restrict__ dst,
    int* __restrict__ deg_out, int* __restrict__ deg_in, int* __restrict__ bucket) {
  int e = blockIdx.x * 256 + threadIdx.x;
  if (e >= NE) return;
  int s = src[e], d = dst[e];
  atomicAdd(&deg_out[s], 1);
  int pos = atomicAdd(&deg_in[d], 1);
  if (pos < CAP) bucket[d * CAP + pos] = s;
}

// ---- norms: deg>0 ? rsqrt(deg) : 0 ----
__global__ __launch_bounds__(256) void k_norm(
    const int* __restrict__ deg_out, const int* __restrict__ deg_in,
    float* __restrict__ out_norm, float* __restrict__ in_norm) {
  int i = blockIdx.x * 256 + threadIdx.x;
  if (i >= NN) return;
  int od = deg_out[i], idg = deg_in[i];
  out_norm[i] = od > 0 ? rsqrtf((float)od) : 0.f;
  in_norm[i]  = idg > 0 ? rsqrtf((float)idg) : 0.f;
}

// ---- aggregation: one wave per dst node, gather + register accumulate ----
__global__ __launch_bounds__(256) void k_agg(
    const float* __restrict__ x, const int* __restrict__ bucket,
    const int* __restrict__ deg_in, const float* __restrict__ out_norm,
    float* __restrict__ agg) {
  int node = blockIdx.x * 4 + (threadIdx.x >> 6);
  int lane = threadIdx.x & 63;
  if (node >= NN) return;
  int n = deg_in[node];
  if (n > CAP) n = CAP;
  const float2* xv = (const float2*)x;
  const int* bk = bucket + node * CAP;
  float2 a0 = make_float2(0.f, 0.f), a1 = make_float2(0.f, 0.f);
  int j = 0;
  for (; j + 2 <= n; j += 2) {
    int s0 = bk[j], s1 = bk[j + 1];
    float w0 = out_norm[s0], w1 = out_norm[s1];
    float2 v0 = xv[s0 * 64 + lane];
    float2 v1 = xv[s1 * 64 + lane];
    a0.x += v0.x * w0; a0.y += v0.y * w0;
    a1.x += v1.x * w1; a1.y += v1.y * w1;
  }
  if (j < n) {
    int s0 = bk[j];
    float w0 = out_norm[s0];
    float2 v0 = xv[s0 * 64 + lane];
    a0.x += v0.x * w0; a0.y += v0.y * w0;
  }
  a0.x += a1.x; a0.y += a1.y;
  ((float2*)agg)[node * 64 + lane] = a0;
}

// ---- GEMM: Y[i][c] = act(in_norm[i] * sum_f A[i][f] W[f][c] + b[c]) ----
template <bool RELU>
__global__ __launch_bounds__(256) void k_gemm(
    const float* __restrict__ A, const float* __restrict__ in_norm,
    const float* __restrict__ W, const float* __restrict__ bias,
    float* __restrict__ Y) {
  __shared__ float As[8][DD];
  int row0 = blockIdx.x * 8;
  int tid = threadIdx.x;
  {
    int r = tid >> 5, c4 = tid & 31;
    int row = row0 + r;
    float4 v = make_float4(0.f, 0.f, 0.f, 0.f);
    if (row < NN) v = ((const float4*)A)[row * 32 + c4];
    ((float4*)(&As[r][0]))[c4] = v;
  }
  __syncthreads();
  int c = tid & 127;
  int rl = tid >> 7;  // 0..1; rows rl, rl+2, rl+4, rl+6
  float acc0 = 0.f, acc1 = 0.f, acc2 = 0.f, acc3 = 0.f;
#pragma unroll 8
  for (int f = 0; f < DD; ++f) {
    float wv = W[f * DD + c];
    acc0 += As[rl + 0][f] * wv;
    acc1 += As[rl + 2][f] * wv;
    acc2 += As[rl + 4][f] * wv;
    acc3 += As[rl + 6][f] * wv;
  }
  float bv = bias[c];
  float accs[4] = {acc0, acc1, acc2, acc3};
#pragma unroll
  for (int k = 0; k < 4; ++k) {
    int row = row0 + rl + 2 * k;
    if (row < NN) {
      float y = accs[k] * in_norm[row] + bv;
      if (RELU) y = fmaxf(y, 0.f);
      Y[row * DD + c] = y;
    }
  }
}

// ---- mean-pool per graph (graph_ids sorted) + classifier ----
__global__ __launch_bounds__(128) void k_pool(
    const float* __restrict__ H, const int* __restrict__ gid,
    const float* __restrict__ Wc, const float* __restrict__ bc,
    float* __restrict__ out) {
  int g = blockIdx.x;
  int f = threadIdx.x;
  int lo, hi;
  { int a = 0, b = NN; while (a < b) { int m = (a + b) >> 1; if (gid[m] < g) a = m + 1; else b = m; } lo = a; }
  { int a = lo, b = NN; while (a < b) { int m = (a + b) >> 1; if (gid[m] <= g) a = m + 1; else b = m; } hi = a; }
  float s = 0.f;
  for (int i = lo; i < hi; ++i) s += H[i * DD + f];
  int cnt = hi - lo;
  float m = s / (float)(cnt > 0 ? cnt : 1);
  float v0 = m * Wc[f * 2 + 0];
  float v1 = m * Wc[f * 2 + 1];
#pragma unroll
  for (int off = 32; off > 0; off >>= 1) {
    v0 += __shfl_down(v0, off);
    v1 += __shfl_down(v1, off);
  }
  __shared__ float p[2][2];
  if ((threadIdx.x & 63) == 0) { p[threadIdx.x >> 6][0] = v0; p[threadIdx.x >> 6][1] = v1; }
  __syncthreads();
  if (threadIdx.x == 0) {
    out[g * 2 + 0] = p[0][0] + p[1][0] + bc[0];
    out[g * 2 + 1] = p[0][1] + p[1][1] + bc[1];
  }
}

extern "C" void kernel_launch(void* const* d_in, const int* in_sizes, int n_in,
                              void* d_out, int out_size, void* d_ws, size_t ws_size,
                              hipStream_t stream) {
  const float* features = (const float*)d_in[0];
  const int* src = (const int*)d_in[1];
  const int* dst = (const int*)d_in[2];
  const int* gid = (const int*)d_in[3];
  const float* W1 = (const float*)d_in[4];
  const float* b1 = (const float*)d_in[5];
  const float* W2 = (const float*)d_in[6];
  const float* b2 = (const float*)d_in[7];
  const float* Wc = (const float*)d_in[8];
  const float* bc = (const float*)d_in[9];
  float* out = (float*)d_out;

  char* ws = (char*)d_ws;
  size_t off = 0;
  auto take = [&](size_t bytes) {
    char* p = ws + off;
    off = (off + bytes + 255) & ~(size_t)255;
    return p;
  };
  int* deg_out   = (int*)take((size_t)NN * 4);
  int* deg_in    = (int*)take((size_t)NN * 4);
  float* out_nrm = (float*)take((size_t)NN * 4);
  float* in_nrm  = (float*)take((size_t)NN * 4);
  int* bucket    = (int*)take((size_t)NN * CAP * 4);
  float* bufA    = (float*)take((size_t)NN * DD * 4);
  float* bufB    = (float*)take((size_t)NN * DD * 4);

  hipMemsetAsync(deg_out, 0, (size_t)NN * 4, stream);
  hipMemsetAsync(deg_in, 0, (size_t)NN * 4, stream);

  k_deg_bucket<<<(NE + 255) / 256, 256, 0, stream>>>(src, dst, deg_out, deg_in, bucket);
  k_norm<<<(NN + 255) / 256, 256, 0, stream>>>(deg_out, deg_in, out_nrm, in_nrm);

  // layer 1: agg(features) -> bufA ; gemm+relu -> bufB (=h1)
  k_agg<<<(NN + 3) / 4, 256, 0, stream>>>(features, bucket, deg_in, out_nrm, bufA);
  k_gemm<true><<<(NN + 7) / 8, 256, 0, stream>>>(bufA, in_nrm, W1, b1, bufB);

  // layer 2: agg(h1) -> bufA ; gemm -> bufB (=h2)
  k_agg<<<(NN + 3) / 4, 256, 0, stream>>>(bufB, bucket, deg_in, out_nrm, bufA);
  k_gemm<false><<<(NN + 7) / 8, 256, 0, stream>>>(bufA, in_nrm, W2, b2, bufB);

  // pool + classify
  k_pool<<<NG, 128, 0, stream>>>(bufB, gid, Wc, bc, out);
}

// Round 3
// 325.424 us; speedup vs baseline: 1.0165x; 1.0165x over previous
//
#include <hip/hip_runtime.h>

#define NN 50000
#define NE 800000
#define NG 512
#define DD 128
#define CAP 64
#define NPART 8
#define PSZ ((NN + NPART - 1) / NPART)   // 6250 nodes per partition
#define EPB 2048                          // edges per block-chunk

// ---- partitioned degree count + bucket scatter ----
// Block b: partition p = b&7 (XCD-local under round-robin dispatch), chunk b>>3.
// Only writes deg/bucket entries for nodes inside its partition -> each cache
// line of deg/bucket is written from (mostly) one XCD -> no cross-XCD
// writeback amplification.
__global__ __launch_bounds__(256) void k_deg_bucket_part(
    const int* __restrict__ src, const int* __restrict__ dst,
    int* __restrict__ deg_out, int* __restrict__ deg_in, int* __restrict__ bucket) {
  int p = blockIdx.x & (NPART - 1);
  int chunk = blockIdx.x >> 3;
  int e0 = chunk * EPB;
  int e1 = e0 + EPB; if (e1 > NE) e1 = NE;
  int lo = p * PSZ;
  int hi = lo + PSZ;
  for (int e = e0 + threadIdx.x; e < e1; e += 256) {
    int s = src[e], d = dst[e];
    if (s >= lo && s < hi) atomicAdd(&deg_out[s], 1);
    if (d >= lo && d < hi) {
      int pos = atomicAdd(&deg_in[d], 1);
      if (pos < CAP) bucket[d * CAP + pos] = s;
    }
  }
}

// ---- norms: deg>0 ? rsqrt(deg) : 0 ----
__global__ __launch_bounds__(256) void k_norm(
    const int* __restrict__ deg_out, const int* __restrict__ deg_in,
    float* __restrict__ out_norm, float* __restrict__ in_norm) {
  int i = blockIdx.x * 256 + threadIdx.x;
  if (i >= NN) return;
  int od = deg_out[i], idg = deg_in[i];
  out_norm[i] = od > 0 ? rsqrtf((float)od) : 0.f;
  in_norm[i]  = idg > 0 ? rsqrtf((float)idg) : 0.f;
}

// ---- aggregation: one wave per dst node, gather + register accumulate ----
__global__ __launch_bounds__(256) void k_agg(
    const float* __restrict__ x, const int* __restrict__ bucket,
    const int* __restrict__ deg_in, const float* __restrict__ out_norm,
    float* __restrict__ agg) {
  int node = blockIdx.x * 4 + (threadIdx.x >> 6);
  int lane = threadIdx.x & 63;
  if (node >= NN) return;
  int n = deg_in[node];
  if (n > CAP) n = CAP;
  const float2* xv = (const float2*)x;
  const int* bk = bucket + node * CAP;
  float2 a0 = make_float2(0.f, 0.f), a1 = make_float2(0.f, 0.f);
  int j = 0;
  for (; j + 2 <= n; j += 2) {
    int s0 = bk[j], s1 = bk[j + 1];
    float w0 = out_norm[s0], w1 = out_norm[s1];
    float2 v0 = xv[s0 * 64 + lane];
    float2 v1 = xv[s1 * 64 + lane];
    a0.x += v0.x * w0; a0.y += v0.y * w0;
    a1.x += v1.x * w1; a1.y += v1.y * w1;
  }
  if (j < n) {
    int s0 = bk[j];
    float w0 = out_norm[s0];
    float2 v0 = xv[s0 * 64 + lane];
    a0.x += v0.x * w0; a0.y += v0.y * w0;
  }
  a0.x += a1.x; a0.y += a1.y;
  ((float2*)agg)[node * 64 + lane] = a0;
}

// ---- GEMM: Y[i][c] = act(in_norm[i] * sum_f A[i][f] W[f][c] + b[c]) ----
template <bool RELU>
__global__ __launch_bounds__(256) void k_gemm(
    const float* __restrict__ A, const float* __restrict__ in_norm,
    const float* __restrict__ W, const float* __restrict__ bias,
    float* __restrict__ Y) {
  __shared__ float As[8][DD];
  int row0 = blockIdx.x * 8;
  int tid = threadIdx.x;
  {
    int r = tid >> 5, c4 = tid & 31;
    int row = row0 + r;
    float4 v = make_float4(0.f, 0.f, 0.f, 0.f);
    if (row < NN) v = ((const float4*)A)[row * 32 + c4];
    ((float4*)(&As[r][0]))[c4] = v;
  }
  __syncthreads();
  int c = tid & 127;
  int rl = tid >> 7;  // 0..1; rows rl, rl+2, rl+4, rl+6
  float acc0 = 0.f, acc1 = 0.f, acc2 = 0.f, acc3 = 0.f;
#pragma unroll 8
  for (int f = 0; f < DD; ++f) {
    float wv = W[f * DD + c];
    acc0 += As[rl + 0][f] * wv;
    acc1 += As[rl + 2][f] * wv;
    acc2 += As[rl + 4][f] * wv;
    acc3 += As[rl + 6][f] * wv;
  }
  float bv = bias[c];
  float accs[4] = {acc0, acc1, acc2, acc3};
#pragma unroll
  for (int k = 0; k < 4; ++k) {
    int row = row0 + rl + 2 * k;
    if (row < NN) {
      float y = accs[k] * in_norm[row] + bv;
      if (RELU) y = fmaxf(y, 0.f);
      Y[row * DD + c] = y;
    }
  }
}

// ---- mean-pool per graph (graph_ids sorted) + classifier ----
__global__ __launch_bounds__(128) void k_pool(
    const float* __restrict__ H, const int* __restrict__ gid,
    const float* __restrict__ Wc, const float* __restrict__ bc,
    float* __restrict__ out) {
  int g = blockIdx.x;
  int f = threadIdx.x;
  int lo, hi;
  { int a = 0, b = NN; while (a < b) { int m = (a + b) >> 1; if (gid[m] < g) a = m + 1; else b = m; } lo = a; }
  { int a = lo, b = NN; while (a < b) { int m = (a + b) >> 1; if (gid[m] <= g) a = m + 1; else b = m; } hi = a; }
  float s = 0.f;
  for (int i = lo; i < hi; ++i) s += H[i * DD + f];
  int cnt = hi - lo;
  float m = s / (float)(cnt > 0 ? cnt : 1);
  float v0 = m * Wc[f * 2 + 0];
  float v1 = m * Wc[f * 2 + 1];
#pragma unroll
  for (int off = 32; off > 0; off >>= 1) {
    v0 += __shfl_down(v0, off);
    v1 += __shfl_down(v1, off);
  }
  __shared__ float p[2][2];
  if ((threadIdx.x & 63) == 0) { p[threadIdx.x >> 6][0] = v0; p[threadIdx.x >> 6][1] = v1; }
  __syncthreads();
  if (threadIdx.x == 0) {
    out[g * 2 + 0] = p[0][0] + p[1][0] + bc[0];
    out[g * 2 + 1] = p[0][1] + p[1][1] + bc[1];
  }
}

extern "C" void kernel_launch(void* const* d_in, const int* in_sizes, int n_in,
                              void* d_out, int out_size, void* d_ws, size_t ws_size,
                              hipStream_t stream) {
  const float* features = (const float*)d_in[0];
  const int* src = (const int*)d_in[1];
  const int* dst = (const int*)d_in[2];
  const int* gid = (const int*)d_in[3];
  const float* W1 = (const float*)d_in[4];
  const float* b1 = (const float*)d_in[5];
  const float* W2 = (const float*)d_in[6];
  const float* b2 = (const float*)d_in[7];
  const float* Wc = (const float*)d_in[8];
  const float* bc = (const float*)d_in[9];
  float* out = (float*)d_out;

  char* ws = (char*)d_ws;
  size_t off = 0;
  auto take = [&](size_t bytes) {
    char* p = ws + off;
    off = (off + bytes + 255) & ~(size_t)255;
    return p;
  };
  int* deg_out   = (int*)take((size_t)NN * 4);
  int* deg_in    = (int*)take((size_t)NN * 4);
  float* out_nrm = (float*)take((size_t)NN * 4);
  float* in_nrm  = (float*)take((size_t)NN * 4);
  int* bucket    = (int*)take((size_t)NN * CAP * 4);
  float* bufA    = (float*)take((size_t)NN * DD * 4);
  float* bufB    = (float*)take((size_t)NN * DD * 4);

  hipMemsetAsync(deg_out, 0, (size_t)NN * 4, stream);
  hipMemsetAsync(deg_in, 0, (size_t)NN * 4, stream);

  int nchunks = (NE + EPB - 1) / EPB;
  k_deg_bucket_part<<<nchunks * NPART, 256, 0, stream>>>(src, dst, deg_out, deg_in, bucket);
  k_norm<<<(NN + 255) / 256, 256, 0, stream>>>(deg_out, deg_in, out_nrm, in_nrm);

  // layer 1: agg(features) -> bufA ; gemm+relu -> bufB (=h1)
  k_agg<<<(NN + 3) / 4, 256, 0, stream>>>(features, bucket, deg_in, out_nrm, bufA);
  k_gemm<true><<<(NN + 7) / 8, 256, 0, stream>>>(bufA, in_nrm, W1, b1, bufB);

  // layer 2: agg(h1) -> bufA ; gemm -> bufB (=h2)
  k_agg<<<(NN + 3) / 4, 256, 0, stream>>>(bufB, bucket, deg_in, out_nrm, bufA);
  k_gemm<false><<<(NN + 7) / 8, 256, 0, stream>>>(bufA, in_nrm, W2, b2, bufB);

  // pool + classify
  k_pool<<<NG, 128, 0, stream>>>(bufB, gid, Wc, bc, out);
}

// Round 4
// 316.933 us; speedup vs baseline: 1.0438x; 1.0268x over previous
//
#include <hip/hip_runtime.h>

#define NN 50000
#define NE 800000
#define NG 512
#define DD 128
#define CAP 64
#define NPART 8
#define PSZ ((NN + NPART - 1) / NPART)   // 6250 nodes per partition
#define EPB 4096                          // edges per block-chunk

typedef int v4i __attribute__((ext_vector_type(4)));

// ---- partitioned degree count + bucket scatter ----
// Block b: partition p = b&7 (XCD-local under round-robin dispatch), chunk b>>3.
// Edge stream read non-temporally (evict-first) so the partition's dirty
// bucket/deg lines stay resident in the XCD-local L2.
__global__ __launch_bounds__(256) void k_deg_bucket_part(
    const int* __restrict__ src, const int* __restrict__ dst,
    int* __restrict__ deg_out, int* __restrict__ deg_in, int* __restrict__ bucket) {
  int p = blockIdx.x & (NPART - 1);
  int chunk = blockIdx.x >> 3;
  int e0 = chunk * EPB;
  int e1 = e0 + EPB; if (e1 > NE) e1 = NE;
  int lo = p * PSZ;
  int hi = lo + PSZ;
  const v4i* s4 = (const v4i*)src;
  const v4i* d4 = (const v4i*)dst;
  int i1 = e1 >> 2;                         // NE % 4 == 0
  for (int i = (e0 >> 2) + threadIdx.x; i < i1; i += 256) {
    v4i sv = __builtin_nontemporal_load(&s4[i]);
    v4i dv = __builtin_nontemporal_load(&d4[i]);
#pragma unroll
    for (int k = 0; k < 4; ++k) {
      int s = sv[k], d = dv[k];
      if (s >= lo && s < hi) atomicAdd(&deg_out[s], 1);
      if (d >= lo && d < hi) {
        int pos = atomicAdd(&deg_in[d], 1);
        if (pos < CAP) bucket[d * CAP + pos] = s;
      }
    }
  }
}

// ---- norms: deg>0 ? rsqrt(deg) : 0 ----
__global__ __launch_bounds__(256) void k_norm(
    const int* __restrict__ deg_out, const int* __restrict__ deg_in,
    float* __restrict__ out_norm, float* __restrict__ in_norm) {
  int i = blockIdx.x * 256 + threadIdx.x;
  if (i >= NN) return;
  int od = deg_out[i], idg = deg_in[i];
  out_norm[i] = od > 0 ? rsqrtf((float)od) : 0.f;
  in_norm[i]  = idg > 0 ? rsqrtf((float)idg) : 0.f;
}

// ---- aggregation: one wave per dst node ----
// Lanes prefetch the whole bucket row + src weights (2 gathers), then the
// K-loop is pure shfl-broadcast + 4 independent float2 gathers (4-deep MLP).
__global__ __launch_bounds__(256) void k_agg(
    const float* __restrict__ x, const int* __restrict__ bucket,
    const int* __restrict__ deg_in, const float* __restrict__ out_norm,
    float* __restrict__ agg) {
  int node = blockIdx.x * 4 + (threadIdx.x >> 6);
  int lane = threadIdx.x & 63;
  if (node >= NN) return;
  int n = deg_in[node];
  if (n > CAP) n = CAP;
  int sl = 0; float wl = 0.f;
  if (lane < n) { sl = bucket[node * CAP + lane]; wl = out_norm[sl]; }
  const float2* xv = (const float2*)x;
  float2 a0 = {0.f, 0.f}, a1 = {0.f, 0.f}, a2 = {0.f, 0.f}, a3 = {0.f, 0.f};
  int j = 0;
  for (; j + 4 <= n; j += 4) {
    int s0 = __shfl(sl, j + 0), s1 = __shfl(sl, j + 1);
    int s2 = __shfl(sl, j + 2), s3 = __shfl(sl, j + 3);
    float w0 = __shfl(wl, j + 0), w1 = __shfl(wl, j + 1);
    float w2 = __shfl(wl, j + 2), w3 = __shfl(wl, j + 3);
    float2 v0 = xv[(size_t)s0 * 64 + lane];
    float2 v1 = xv[(size_t)s1 * 64 + lane];
    float2 v2 = xv[(size_t)s2 * 64 + lane];
    float2 v3 = xv[(size_t)s3 * 64 + lane];
    a0.x += v0.x * w0; a0.y += v0.y * w0;
    a1.x += v1.x * w1; a1.y += v1.y * w1;
    a2.x += v2.x * w2; a2.y += v2.y * w2;
    a3.x += v3.x * w3; a3.y += v3.y * w3;
  }
  for (; j < n; ++j) {
    int s0 = __shfl(sl, j);
    float w0 = __shfl(wl, j);
    float2 v0 = xv[(size_t)s0 * 64 + lane];
    a0.x += v0.x * w0; a0.y += v0.y * w0;
  }
  a0.x += a1.x + a2.x + a3.x;
  a0.y += a1.y + a2.y + a3.y;
  ((float2*)agg)[(size_t)node * 64 + lane] = a0;
}

// ---- GEMM: Y[i][c] = act(in_norm[i] * sum_f A[i][f] W[f][c] + b[c]) ----
template <bool RELU>
__global__ __launch_bounds__(256) void k_gemm(
    const float* __restrict__ A, const float* __restrict__ in_norm,
    const float* __restrict__ W, const float* __restrict__ bias,
    float* __restrict__ Y) {
  __shared__ float As[8][DD];
  int row0 = blockIdx.x * 8;
  int tid = threadIdx.x;
  {
    int r = tid >> 5, c4 = tid & 31;
    int row = row0 + r;
    float4 v = make_float4(0.f, 0.f, 0.f, 0.f);
    if (row < NN) v = ((const float4*)A)[row * 32 + c4];
    ((float4*)(&As[r][0]))[c4] = v;
  }
  __syncthreads();
  int c = tid & 127;
  int rl = tid >> 7;  // 0..1; rows rl, rl+2, rl+4, rl+6
  float acc0 = 0.f, acc1 = 0.f, acc2 = 0.f, acc3 = 0.f;
#pragma unroll 8
  for (int f = 0; f < DD; ++f) {
    float wv = W[f * DD + c];
    acc0 += As[rl + 0][f] * wv;
    acc1 += As[rl + 2][f] * wv;
    acc2 += As[rl + 4][f] * wv;
    acc3 += As[rl + 6][f] * wv;
  }
  float bv = bias[c];
  float accs[4] = {acc0, acc1, acc2, acc3};
#pragma unroll
  for (int k = 0; k < 4; ++k) {
    int row = row0 + rl + 2 * k;
    if (row < NN) {
      float y = accs[k] * in_norm[row] + bv;
      if (RELU) y = fmaxf(y, 0.f);
      Y[row * DD + c] = y;
    }
  }
}

// ---- mean-pool per graph (graph_ids sorted) + classifier ----
__global__ __launch_bounds__(128) void k_pool(
    const float* __restrict__ H, const int* __restrict__ gid,
    const float* __restrict__ Wc, const float* __restrict__ bc,
    float* __restrict__ out) {
  int g = blockIdx.x;
  int f = threadIdx.x;
  int lo, hi;
  { int a = 0, b = NN; while (a < b) { int m = (a + b) >> 1; if (gid[m] < g) a = m + 1; else b = m; } lo = a; }
  { int a = lo, b = NN; while (a < b) { int m = (a + b) >> 1; if (gid[m] <= g) a = m + 1; else b = m; } hi = a; }
  float s = 0.f;
  for (int i = lo; i < hi; ++i) s += H[i * DD + f];
  int cnt = hi - lo;
  float m = s / (float)(cnt > 0 ? cnt : 1);
  float v0 = m * Wc[f * 2 + 0];
  float v1 = m * Wc[f * 2 + 1];
#pragma unroll
  for (int off = 32; off > 0; off >>= 1) {
    v0 += __shfl_down(v0, off);
    v1 += __shfl_down(v1, off);
  }
  __shared__ float p[2][2];
  if ((threadIdx.x & 63) == 0) { p[threadIdx.x >> 6][0] = v0; p[threadIdx.x >> 6][1] = v1; }
  __syncthreads();
  if (threadIdx.x == 0) {
    out[g * 2 + 0] = p[0][0] + p[1][0] + bc[0];
    out[g * 2 + 1] = p[0][1] + p[1][1] + bc[1];
  }
}

extern "C" void kernel_launch(void* const* d_in, const int* in_sizes, int n_in,
                              void* d_out, int out_size, void* d_ws, size_t ws_size,
                              hipStream_t stream) {
  const float* features = (const float*)d_in[0];
  const int* src = (const int*)d_in[1];
  const int* dst = (const int*)d_in[2];
  const int* gid = (const int*)d_in[3];
  const float* W1 = (const float*)d_in[4];
  const float* b1 = (const float*)d_in[5];
  const float* W2 = (const float*)d_in[6];
  const float* b2 = (const float*)d_in[7];
  const float* Wc = (const float*)d_in[8];
  const float* bc = (const float*)d_in[9];
  float* out = (float*)d_out;

  char* ws = (char*)d_ws;
  size_t off = 0;
  auto take = [&](size_t bytes) {
    char* p = ws + off;
    off = (off + bytes + 255) & ~(size_t)255;
    return p;
  };
  int* deg_out   = (int*)take((size_t)NN * 4);
  int* deg_in    = (int*)take((size_t)NN * 4);
  float* out_nrm = (float*)take((size_t)NN * 4);
  float* in_nrm  = (float*)take((size_t)NN * 4);
  int* bucket    = (int*)take((size_t)NN * CAP * 4);
  float* bufA    = (float*)take((size_t)NN * DD * 4);
  float* bufB    = (float*)take((size_t)NN * DD * 4);

  hipMemsetAsync(deg_out, 0, (size_t)NN * 4, stream);
  hipMemsetAsync(deg_in, 0, (size_t)NN * 4, stream);

  int nchunks = (NE + EPB - 1) / EPB;
  k_deg_bucket_part<<<nchunks * NPART, 256, 0, stream>>>(src, dst, deg_out, deg_in, bucket);
  k_norm<<<(NN + 255) / 256, 256, 0, stream>>>(deg_out, deg_in, out_nrm, in_nrm);

  // layer 1: agg(features) -> bufA ; gemm+relu -> bufB (=h1)
  k_agg<<<(NN + 3) / 4, 256, 0, stream>>>(features, bucket, deg_in, out_nrm, bufA);
  k_gemm<true><<<(NN + 7) / 8, 256, 0, stream>>>(bufA, in_nrm, W1, b1, bufB);

  // layer 2: agg(h1) -> bufA ; gemm -> bufB (=h2)
  k_agg<<<(NN + 3) / 4, 256, 0, stream>>>(bufB, bucket, deg_in, out_nrm, bufA);
  k_gemm<false><<<(NN + 7) / 8, 256, 0, stream>>>(bufA, in_nrm, W2, b2, bufB);

  // pool + classify
  k_pool<<<NG, 128, 0, stream>>>(bufB, gid, Wc, bc, out);
}